// Round 4
// baseline (462.168 us; speedup 1.0000x reference)
//
#include <hip/hip_runtime.h>
#include <hip/hip_bf16.h>
#include <math.h>

#define NPTS 4096
#define SDIM 128
#define NV 6
#define KTOP 5
#define IMG_ELEMS (NV * SDIM * SDIM * 3)   // 294912

// fp32(0.01*0.01) = 9.99999975e-05 == fp32 literal 1e-4f
#define R2F 1e-4f

struct CamParams { float R[NV][9]; float T[NV][3]; };

// ---------------- prep: sigmoid colors + per-view transform ----------------
// Inputs float32; outputs float32 (reference output dtype).
__global__ __launch_bounds__(256) void prep_kernel(
    const float* __restrict__ pcd,
    const float* __restrict__ add0,
    const float* __restrict__ add1,
    float* __restrict__ out_colors,
    float4* __restrict__ pview,
    CamParams cams) {
  int i = blockIdx.x * blockDim.x + threadIdx.x;
  if (i >= NPTS) return;
  float p0 = pcd[3 * i + 0];
  float p1 = pcd[3 * i + 1];
  float p2 = pcd[3 * i + 2];
  float xv = add0[i] + add1[i];          // init_colors + displace (commutative)
  float c = 1.0f / (1.0f + expf(-xv));
  out_colors[i] = c;
#pragma unroll
  for (int v = 0; v < NV; v++) {
    const float* R = cams.R[v];
    const float* T = cams.T[v];
    // pv[i] = sum_j p[j] * R[j][i] + T[i]   (R stored row-major R[j*3+i])
    float px = p0 * R[0] + p1 * R[3] + p2 * R[6] + T[0];
    float py = p0 * R[1] + p1 * R[4] + p2 * R[7] + T[1];
    float pz = p0 * R[2] + p1 * R[5] + p2 * R[8] + T[2];
    if (!(pz > 0.01f && pz < 100.0f)) px = 1e9f;  // fold z-validity into miss
    pview[v * NPTS + i] = make_float4(px, py, pz, c);
  }
}

// ---------------- render: per-pixel top-5 by z + alpha composite ----------------
__global__ __launch_bounds__(256) void render_kernel(
    const float4* __restrict__ pview,
    float* __restrict__ out) {
  int v = blockIdx.x >> 6;         // 64 pixel-blocks per view
  int pblk = blockIdx.x & 63;
  int pidx = pblk * 256 + threadIdx.x;      // linear pixel: h*128 + w
  int h = pidx >> 7;
  int w = pidx & 127;
  float xf = (float)(127 - 2 * w) * (1.0f / 128.0f);  // exact dyadic, matches ref
  float yf = (float)(127 - 2 * h) * (1.0f / 128.0f);

  const float4* __restrict__ pts = pview + v * NPTS;

  // top-5 sorted ascending by z; stable (index order) via strict < comparisons
  float zk[KTOP], wk[KTOP], ck[KTOP];
#pragma unroll
  for (int k = 0; k < KTOP; k++) { zk[k] = 1e30f; wk[k] = 0.0f; ck[k] = 0.0f; }

#pragma unroll 4
  for (int i = 0; i < NPTS; i++) {
    float4 P = pts[i];
    float dx = xf - P.x;
    float dy = yf - P.y;
    float d2 = dx * dx + dy * dy;
    if (d2 < R2F) {                 // strict, matches hit = d2 < R2
      float wgt = 1.0f - d2 / R2F;  // exact ref arithmetic (division)
      float z = P.z;
      if (z < zk[KTOP - 1]) {       // strictly better than current worst
        zk[KTOP - 1] = z; wk[KTOP - 1] = wgt; ck[KTOP - 1] = P.w;
#pragma unroll
        for (int k = KTOP - 1; k > 0; k--) {
          if (zk[k] < zk[k - 1]) {  // strict < keeps equal-z stable (lower idx first)
            float tz = zk[k]; zk[k] = zk[k - 1]; zk[k - 1] = tz;
            float tw = wk[k]; wk[k] = wk[k - 1]; wk[k - 1] = tw;
            float tc = ck[k]; ck[k] = ck[k - 1]; ck[k - 1] = tc;
          }
        }
      }
    }
  }

  // front-to-back alpha composite; empty slots have w=0 (no-op), matching ref
  float acc = 0.0f, pre = 1.0f;
#pragma unroll
  for (int k = 0; k < KTOP; k++) {
    acc += wk[k] * pre * ck[k];
    pre *= (1.0f - wk[k]);
  }

  int base = v * (SDIM * SDIM * 3) + pidx * 3;
  out[base + 0] = acc;
  out[base + 1] = acc;
  out[base + 2] = acc;
}

// ---------------- host: camera R,T from compile-time constants ----------------
static void compute_cams(CamParams* cp) {
  const double views[NV] = {45.0, 90.0, 135.0, 225.0, 270.0, 315.0};
  const double deg = M_PI / 180.0;
  const double elev = 15.0 * deg;
  const double dist = 1.5;
  for (int v = 0; v < NV; v++) {
    double az = views[v] * deg;
    double C[3] = {dist * cos(elev) * sin(az), dist * sin(elev),
                   dist * cos(elev) * cos(az)};
    double n = sqrt(C[0] * C[0] + C[1] * C[1] + C[2] * C[2]);
    double z[3] = {-C[0] / n, -C[1] / n, -C[2] / n};
    double up[3] = {0.0, 1.0, 0.0};
    double x[3] = {up[1] * z[2] - up[2] * z[1],
                   up[2] * z[0] - up[0] * z[2],
                   up[0] * z[1] - up[1] * z[0]};
    double nx = sqrt(x[0] * x[0] + x[1] * x[1] + x[2] * x[2]);
    x[0] /= nx; x[1] /= nx; x[2] /= nx;
    double y[3] = {z[1] * x[2] - z[2] * x[1],
                   z[2] * x[0] - z[0] * x[2],
                   z[0] * x[1] - z[1] * x[0]};
    double ny = sqrt(y[0] * y[0] + y[1] * y[1] + y[2] * y[2]);
    y[0] /= ny; y[1] /= ny; y[2] /= ny;
    double Rm[3][3];  // columns x, y, z  ->  Rm[j][i]
    for (int j = 0; j < 3; j++) {
      Rm[j][0] = x[j]; Rm[j][1] = y[j]; Rm[j][2] = z[j];
    }
    for (int j = 0; j < 3; j++)
      for (int i = 0; i < 3; i++)
        cp->R[v][j * 3 + i] = (float)Rm[j][i];
    for (int i = 0; i < 3; i++)
      cp->T[v][i] = (float)(-(C[0] * Rm[0][i] + C[1] * Rm[1][i] + C[2] * Rm[2][i]));
  }
}

extern "C" void kernel_launch(void* const* d_in, const int* in_sizes, int n_in,
                              void* d_out, int out_size, void* d_ws, size_t ws_size,
                              hipStream_t stream) {
  CamParams cp;
  compute_cams(&cp);

  // Identify inputs by size (robust to ordering): pcd is the unique 3*NPTS
  // array; the two NPTS arrays are symmetric addends (init_colors + displace).
  const float* pcd = nullptr;
  const float* adds[2] = {nullptr, nullptr};
  int na = 0;
  for (int i = 0; i < n_in; i++) {
    if (in_sizes[i] == 3 * NPTS) pcd = (const float*)d_in[i];
    else if (na < 2) adds[na++] = (const float*)d_in[i];
  }
  if (!pcd || na < 2) { pcd = (const float*)d_in[0];
                        adds[0] = (const float*)d_in[1];
                        adds[1] = (const float*)d_in[2]; }

  float* out = (float*)d_out;              // reference output dtype = float32
  float4* pview = (float4*)d_ws;           // 6*4096*16 = 384 KB scratch

  prep_kernel<<<NPTS / 256, 256, 0, stream>>>(pcd, adds[0], adds[1],
                                              out + IMG_ELEMS, pview, cp);
  render_kernel<<<NV * 64, 256, 0, stream>>>(pview, out);
}

// Round 5
// 148.659 us; speedup vs baseline: 3.1089x; 3.1089x over previous
//
#include <hip/hip_runtime.h>
#include <hip/hip_bf16.h>
#include <math.h>

#define NPTS 4096
#define SDIM 128
#define NV 6
#define KTOP 5
#define IMG_ELEMS (NV * SDIM * SDIM * 3)   // 294912

// fp32(0.01*0.01) = 9.99999975e-05 == fp32 literal 1e-4f
#define R2F 1e-4f
#define RMARG 0.0102f        // conservative bin margin (> radius 0.01)

#define TILE 8               // 8x8 pixel tiles
#define TPV 16               // tiles per axis (128/8)
#define NTILES (NV * TPV * TPV)   // 1536

struct CamParams { float R[NV][9]; float T[NV][3]; };

// ============ fused prep + binning: sigmoid, transform, tile scatter ============
__global__ __launch_bounds__(256) void prep_bin_kernel(
    const float* __restrict__ pcd,
    const float* __restrict__ add0,
    const float* __restrict__ add1,
    float* __restrict__ out_colors,
    int* __restrict__ counts,          // [NTILES], pre-zeroed
    float4* __restrict__ lists,        // [NTILES * cap]
    int cap,
    CamParams cams) {
  int i = blockIdx.x * blockDim.x + threadIdx.x;
  if (i >= NPTS) return;
  float p0 = pcd[3 * i + 0];
  float p1 = pcd[3 * i + 1];
  float p2 = pcd[3 * i + 2];
  float xv = add0[i] + add1[i];        // init_colors + displace (commutative)
  float c = 1.0f / (1.0f + expf(-xv));
  out_colors[i] = c;
#pragma unroll
  for (int v = 0; v < NV; v++) {
    const float* R = cams.R[v];
    const float* T = cams.T[v];
    float px = p0 * R[0] + p1 * R[3] + p2 * R[6] + T[0];
    float py = p0 * R[1] + p1 * R[4] + p2 * R[7] + T[1];
    float pz = p0 * R[2] + p1 * R[5] + p2 * R[8] + T[2];
    if (!(pz > 0.01f && pz < 100.0f)) continue;   // invalid -> never hits
    // pixel w hits if |xf[w]-px|<r with xf[w]=(127-2w)/128 (decreasing in w)
    int wlo = (int)floorf((127.0f - 128.0f * (px + RMARG)) * 0.5f);
    int whi = (int)ceilf ((127.0f - 128.0f * (px - RMARG)) * 0.5f);
    int hlo = (int)floorf((127.0f - 128.0f * (py + RMARG)) * 0.5f);
    int hhi = (int)ceilf ((127.0f - 128.0f * (py - RMARG)) * 0.5f);
    if (whi < 0 || wlo > 127 || hhi < 0 || hlo > 127) continue;
    int txlo = max(0, wlo >> 3), txhi = min(TPV - 1, whi >> 3);
    int tylo = max(0, hlo >> 3), tyhi = min(TPV - 1, hhi >> 3);
    float4 payload = make_float4(px, py, pz, c);
    for (int ty = tylo; ty <= tyhi; ty++)
      for (int tx = txlo; tx <= txhi; tx++) {
        int tile = v * (TPV * TPV) + ty * TPV + tx;
        int idx = atomicAdd(&counts[tile], 1);
        if (idx < cap) lists[(size_t)tile * cap + idx] = payload;
      }
  }
}

// ============ binned render: one 8x8 tile per 64-thread block ============
__global__ __launch_bounds__(64) void render_binned_kernel(
    const int* __restrict__ counts,
    const float4* __restrict__ lists,
    int cap,
    float* __restrict__ out) {
  int b = blockIdx.x;
  int v = b >> 8;                      // 256 tiles per view
  int t = b & 255;
  int ty = t >> 4, tx = t & 15;
  int lane = threadIdx.x;
  int h = ty * TILE + (lane >> 3);
  int w = tx * TILE + (lane & 7);
  float xf = (float)(127 - 2 * w) * (1.0f / 128.0f);
  float yf = (float)(127 - 2 * h) * (1.0f / 128.0f);

  int count = counts[b];
  if (count > cap) count = cap;
  const float4* __restrict__ list = lists + (size_t)b * cap;

  float zk[KTOP], wk[KTOP], ck[KTOP];
#pragma unroll
  for (int k = 0; k < KTOP; k++) { zk[k] = 1e30f; wk[k] = 0.0f; ck[k] = 0.0f; }

  __shared__ float4 cbuf[64];
  for (int c0 = 0; c0 < count; c0 += 64) {
    int i = c0 + lane;
    if (i < count) cbuf[lane] = list[i];
    __syncthreads();
    int n = min(64, count - c0);
#pragma unroll 4
    for (int j = 0; j < n; j++) {
      float4 P = cbuf[j];
      float dx = xf - P.x;
      float dy = yf - P.y;
      float d2 = dx * dx + dy * dy;
      if (d2 < R2F) {                 // strict, matches ref hit = d2 < R2
        float wgt = 1.0f - d2 / R2F;  // exact ref arithmetic
        float z = P.z;
        if (z < zk[KTOP - 1]) {
          zk[KTOP - 1] = z; wk[KTOP - 1] = wgt; ck[KTOP - 1] = P.w;
#pragma unroll
          for (int k = KTOP - 1; k > 0; k--) {
            if (zk[k] < zk[k - 1]) {
              float tz = zk[k]; zk[k] = zk[k - 1]; zk[k - 1] = tz;
              float tw = wk[k]; wk[k] = wk[k - 1]; wk[k - 1] = tw;
              float tc = ck[k]; ck[k] = ck[k - 1]; ck[k - 1] = tc;
            }
          }
        }
      }
    }
    __syncthreads();
  }

  float acc = 0.0f, pre = 1.0f;
#pragma unroll
  for (int k = 0; k < KTOP; k++) {
    acc += wk[k] * pre * ck[k];
    pre *= (1.0f - wk[k]);
  }

  int base = v * (SDIM * SDIM * 3) + (h * SDIM + w) * 3;
  out[base + 0] = acc;
  out[base + 1] = acc;
  out[base + 2] = acc;
}

// ============ fallback (round-4 proven path) for small ws ============
__global__ __launch_bounds__(256) void prep_kernel(
    const float* __restrict__ pcd, const float* __restrict__ add0,
    const float* __restrict__ add1, float* __restrict__ out_colors,
    float4* __restrict__ pview, CamParams cams) {
  int i = blockIdx.x * blockDim.x + threadIdx.x;
  if (i >= NPTS) return;
  float p0 = pcd[3 * i + 0], p1 = pcd[3 * i + 1], p2 = pcd[3 * i + 2];
  float xv = add0[i] + add1[i];
  float c = 1.0f / (1.0f + expf(-xv));
  out_colors[i] = c;
#pragma unroll
  for (int v = 0; v < NV; v++) {
    const float* R = cams.R[v];
    const float* T = cams.T[v];
    float px = p0 * R[0] + p1 * R[3] + p2 * R[6] + T[0];
    float py = p0 * R[1] + p1 * R[4] + p2 * R[7] + T[1];
    float pz = p0 * R[2] + p1 * R[5] + p2 * R[8] + T[2];
    if (!(pz > 0.01f && pz < 100.0f)) px = 1e9f;
    pview[v * NPTS + i] = make_float4(px, py, pz, c);
  }
}

__global__ __launch_bounds__(256) void render_kernel(
    const float4* __restrict__ pview, float* __restrict__ out) {
  int v = blockIdx.x >> 6;
  int pidx = (blockIdx.x & 63) * 256 + threadIdx.x;
  int h = pidx >> 7, w = pidx & 127;
  float xf = (float)(127 - 2 * w) * (1.0f / 128.0f);
  float yf = (float)(127 - 2 * h) * (1.0f / 128.0f);
  const float4* __restrict__ pts = pview + v * NPTS;
  float zk[KTOP], wk[KTOP], ck[KTOP];
#pragma unroll
  for (int k = 0; k < KTOP; k++) { zk[k] = 1e30f; wk[k] = 0.0f; ck[k] = 0.0f; }
#pragma unroll 4
  for (int i = 0; i < NPTS; i++) {
    float4 P = pts[i];
    float dx = xf - P.x, dy = yf - P.y;
    float d2 = dx * dx + dy * dy;
    if (d2 < R2F) {
      float wgt = 1.0f - d2 / R2F;
      float z = P.z;
      if (z < zk[KTOP - 1]) {
        zk[KTOP - 1] = z; wk[KTOP - 1] = wgt; ck[KTOP - 1] = P.w;
#pragma unroll
        for (int k = KTOP - 1; k > 0; k--) {
          if (zk[k] < zk[k - 1]) {
            float tz = zk[k]; zk[k] = zk[k - 1]; zk[k - 1] = tz;
            float tw = wk[k]; wk[k] = wk[k - 1]; wk[k - 1] = tw;
            float tc = ck[k]; ck[k] = ck[k - 1]; ck[k - 1] = tc;
          }
        }
      }
    }
  }
  float acc = 0.0f, pre = 1.0f;
#pragma unroll
  for (int k = 0; k < KTOP; k++) { acc += wk[k] * pre * ck[k]; pre *= (1.0f - wk[k]); }
  int base = v * (SDIM * SDIM * 3) + pidx * 3;
  out[base + 0] = acc; out[base + 1] = acc; out[base + 2] = acc;
}

// ---------------- host: camera R,T from compile-time constants ----------------
static void compute_cams(CamParams* cp) {
  const double views[NV] = {45.0, 90.0, 135.0, 225.0, 270.0, 315.0};
  const double deg = M_PI / 180.0;
  const double elev = 15.0 * deg;
  const double dist = 1.5;
  for (int v = 0; v < NV; v++) {
    double az = views[v] * deg;
    double C[3] = {dist * cos(elev) * sin(az), dist * sin(elev),
                   dist * cos(elev) * cos(az)};
    double n = sqrt(C[0] * C[0] + C[1] * C[1] + C[2] * C[2]);
    double z[3] = {-C[0] / n, -C[1] / n, -C[2] / n};
    double up[3] = {0.0, 1.0, 0.0};
    double x[3] = {up[1] * z[2] - up[2] * z[1],
                   up[2] * z[0] - up[0] * z[2],
                   up[0] * z[1] - up[1] * z[0]};
    double nx = sqrt(x[0] * x[0] + x[1] * x[1] + x[2] * x[2]);
    x[0] /= nx; x[1] /= nx; x[2] /= nx;
    double y[3] = {z[1] * x[2] - z[2] * x[1],
                   z[2] * x[0] - z[0] * x[2],
                   z[0] * x[1] - z[1] * x[0]};
    double ny = sqrt(y[0] * y[0] + y[1] * y[1] + y[2] * y[2]);
    y[0] /= ny; y[1] /= ny; y[2] /= ny;
    double Rm[3][3];
    for (int j = 0; j < 3; j++) { Rm[j][0] = x[j]; Rm[j][1] = y[j]; Rm[j][2] = z[j]; }
    for (int j = 0; j < 3; j++)
      for (int i = 0; i < 3; i++)
        cp->R[v][j * 3 + i] = (float)Rm[j][i];
    for (int i = 0; i < 3; i++)
      cp->T[v][i] = (float)(-(C[0] * Rm[0][i] + C[1] * Rm[1][i] + C[2] * Rm[2][i]));
  }
}

extern "C" void kernel_launch(void* const* d_in, const int* in_sizes, int n_in,
                              void* d_out, int out_size, void* d_ws, size_t ws_size,
                              hipStream_t stream) {
  CamParams cp;
  compute_cams(&cp);

  // Identify inputs by size (robust to ordering): pcd is the unique 3*NPTS
  // array; the two NPTS arrays are symmetric addends.
  const float* pcd = nullptr;
  const float* adds[2] = {nullptr, nullptr};
  int na = 0;
  for (int i = 0; i < n_in; i++) {
    if (in_sizes[i] == 3 * NPTS) pcd = (const float*)d_in[i];
    else if (na < 2) adds[na++] = (const float*)d_in[i];
  }
  if (!pcd || na < 2) { pcd = (const float*)d_in[0];
                        adds[0] = (const float*)d_in[1];
                        adds[1] = (const float*)d_in[2]; }

  float* out = (float*)d_out;
  float* out_colors = out + IMG_ELEMS;

  // ws layout (binned path): [0,6144) counts | [8192, 8192+NTILES*cap*16) lists
  const size_t list_off = 8192;
  size_t avail = (ws_size > list_off) ? (ws_size - list_off) : 0;
  int cap = (int)(avail / ((size_t)NTILES * sizeof(float4)));
  if (cap > 1024) cap = 1024;

  if (cap >= 256) {
    int* counts = (int*)d_ws;
    float4* lists = (float4*)((char*)d_ws + list_off);
    hipMemsetAsync(counts, 0, NTILES * sizeof(int), stream);
    prep_bin_kernel<<<NPTS / 256, 256, 0, stream>>>(pcd, adds[0], adds[1],
                                                    out_colors, counts, lists,
                                                    cap, cp);
    render_binned_kernel<<<NTILES, 64, 0, stream>>>(counts, lists, cap, out);
  } else {
    // fallback: proven brute-force path (needs only 384 KB)
    float4* pview = (float4*)d_ws;
    prep_kernel<<<NPTS / 256, 256, 0, stream>>>(pcd, adds[0], adds[1],
                                                out_colors, pview, cp);
    render_kernel<<<NV * 64, 256, 0, stream>>>(pview, out);
  }
}

// Round 6
// 133.097 us; speedup vs baseline: 3.4724x; 1.1169x over previous
//
#include <hip/hip_runtime.h>
#include <hip/hip_bf16.h>
#include <math.h>

#define NPTS 4096
#define SDIM 128
#define NV 6
#define KTOP 5
#define IMG_ELEMS (NV * SDIM * SDIM * 3)   // 294912

// fp32(0.01*0.01) = 9.99999975e-05 == fp32 literal 1e-4f
#define R2F 1e-4f
#define RMARG 0.0102f        // conservative candidate margin (> radius 0.01)

#define RB 16                // block region: 16x16 pixels
#define BPA 8                // blocks per axis (128/16)
#define NBLK (NV * BPA * BPA)   // 384 blocks
#define CAP 2048             // LDS candidate capacity (worst case ~530 expected)

struct CamParams { float R[NV][9]; float T[NV][3]; };

// ======== fully fused: transform + LDS-bin + top-5 + composite ========
__global__ __launch_bounds__(256) void fused_render_kernel(
    const float* __restrict__ pcd,
    const float* __restrict__ add0,
    const float* __restrict__ add1,
    float* __restrict__ out,           // images [6,128,128,3]
    float* __restrict__ out_colors,    // colors [4096]
    CamParams cams) {
  int b = blockIdx.x;
  int v = b >> 6;                      // 64 blocks per view
  int t = b & 63;
  int ty = t >> 3, tx = t & 7;
  int tid = threadIdx.x;
  int h = ty * RB + (tid >> 4);
  int w = tx * RB + (tid & 15);
  float xf = (float)(127 - 2 * w) * (1.0f / 128.0f);
  float yf = (float)(127 - 2 * h) * (1.0f / 128.0f);

  // region NDC bounds (xf decreasing in w): w0=tx*16 .. w0+15
  float xhi = (float)(127 - 2 * (tx * RB)) * (1.0f / 128.0f) + RMARG;
  float xlo = (float)(127 - 2 * (tx * RB + RB - 1)) * (1.0f / 128.0f) - RMARG;
  float yhi = (float)(127 - 2 * (ty * RB)) * (1.0f / 128.0f) + RMARG;
  float ylo = (float)(127 - 2 * (ty * RB + RB - 1)) * (1.0f / 128.0f) - RMARG;

  __shared__ float4 cand[CAP];
  __shared__ int cnt;
  if (tid == 0) cnt = 0;
  __syncthreads();

  const float* R = cams.R[v];
  const float* T = cams.T[v];

  // transform all points; append region candidates to LDS
#pragma unroll 4
  for (int k = 0; k < NPTS / 256; k++) {
    int i = k * 256 + tid;
    float p0 = pcd[3 * i + 0];
    float p1 = pcd[3 * i + 1];
    float p2 = pcd[3 * i + 2];
    float sv = add0[i] + add1[i];        // init_colors + displace (commutative)
    float c = 1.0f / (1.0f + expf(-sv));
    if (b < 16 && k == b) out_colors[i] = c;   // blocks 0..15 emit colors once
    float px = p0 * R[0] + p1 * R[3] + p2 * R[6] + T[0];
    float py = p0 * R[1] + p1 * R[4] + p2 * R[7] + T[1];
    float pz = p0 * R[2] + p1 * R[5] + p2 * R[8] + T[2];
    if (pz > 0.01f && pz < 100.0f &&
        px > xlo && px < xhi && py > ylo && py < yhi) {
      int idx = atomicAdd(&cnt, 1);
      if (idx < CAP) cand[idx] = make_float4(px, py, pz, c);
    }
  }
  __syncthreads();

  int n = cnt < CAP ? cnt : CAP;

  // per-pixel top-5 by z (ascending); ties measure-zero in continuous data
  float zk[KTOP], wk[KTOP], ck[KTOP];
#pragma unroll
  for (int k = 0; k < KTOP; k++) { zk[k] = 1e30f; wk[k] = 0.0f; ck[k] = 0.0f; }

  for (int j = 0; j < n; j++) {
    float4 P = cand[j];                 // same-address broadcast, conflict-free
    float dx = xf - P.x;
    float dy = yf - P.y;
    float d2 = dx * dx + dy * dy;
    if (d2 < R2F) {                     // strict, matches ref hit = d2 < R2
      float wgt = 1.0f - d2 / R2F;      // exact ref arithmetic
      float z = P.z;
      if (z < zk[KTOP - 1]) {
        zk[KTOP - 1] = z; wk[KTOP - 1] = wgt; ck[KTOP - 1] = P.w;
#pragma unroll
        for (int k = KTOP - 1; k > 0; k--) {
          if (zk[k] < zk[k - 1]) {
            float tz = zk[k]; zk[k] = zk[k - 1]; zk[k - 1] = tz;
            float tw = wk[k]; wk[k] = wk[k - 1]; wk[k - 1] = tw;
            float tc = ck[k]; ck[k] = ck[k - 1]; ck[k - 1] = tc;
          }
        }
      }
    }
  }

  // front-to-back alpha composite; empty slots w=0 are no-ops (matches ref)
  float acc = 0.0f, pre = 1.0f;
#pragma unroll
  for (int k = 0; k < KTOP; k++) {
    acc += wk[k] * pre * ck[k];
    pre *= (1.0f - wk[k]);
  }

  int base = v * (SDIM * SDIM * 3) + (h * SDIM + w) * 3;
  out[base + 0] = acc;
  out[base + 1] = acc;
  out[base + 2] = acc;
}

// ---------------- host: camera R,T from compile-time constants ----------------
static void compute_cams(CamParams* cp) {
  const double views[NV] = {45.0, 90.0, 135.0, 225.0, 270.0, 315.0};
  const double deg = M_PI / 180.0;
  const double elev = 15.0 * deg;
  const double dist = 1.5;
  for (int v = 0; v < NV; v++) {
    double az = views[v] * deg;
    double C[3] = {dist * cos(elev) * sin(az), dist * sin(elev),
                   dist * cos(elev) * cos(az)};
    double n = sqrt(C[0] * C[0] + C[1] * C[1] + C[2] * C[2]);
    double z[3] = {-C[0] / n, -C[1] / n, -C[2] / n};
    double up[3] = {0.0, 1.0, 0.0};
    double x[3] = {up[1] * z[2] - up[2] * z[1],
                   up[2] * z[0] - up[0] * z[2],
                   up[0] * z[1] - up[1] * z[0]};
    double nx = sqrt(x[0] * x[0] + x[1] * x[1] + x[2] * x[2]);
    x[0] /= nx; x[1] /= nx; x[2] /= nx;
    double y[3] = {z[1] * x[2] - z[2] * x[1],
                   z[2] * x[0] - z[0] * x[2],
                   z[0] * x[1] - z[1] * x[0]};
    double ny = sqrt(y[0] * y[0] + y[1] * y[1] + y[2] * y[2]);
    y[0] /= ny; y[1] /= ny; y[2] /= ny;
    double Rm[3][3];  // columns x, y, z
    for (int j = 0; j < 3; j++) { Rm[j][0] = x[j]; Rm[j][1] = y[j]; Rm[j][2] = z[j]; }
    for (int j = 0; j < 3; j++)
      for (int i = 0; i < 3; i++)
        cp->R[v][j * 3 + i] = (float)Rm[j][i];
    for (int i = 0; i < 3; i++)
      cp->T[v][i] = (float)(-(C[0] * Rm[0][i] + C[1] * Rm[1][i] + C[2] * Rm[2][i]));
  }
}

extern "C" void kernel_launch(void* const* d_in, const int* in_sizes, int n_in,
                              void* d_out, int out_size, void* d_ws, size_t ws_size,
                              hipStream_t stream) {
  CamParams cp;
  compute_cams(&cp);

  // Identify inputs by size (robust to ordering): pcd is the unique 3*NPTS
  // array; the two NPTS arrays are symmetric addends (init_colors + displace).
  const float* pcd = nullptr;
  const float* adds[2] = {nullptr, nullptr};
  int na = 0;
  for (int i = 0; i < n_in; i++) {
    if (in_sizes[i] == 3 * NPTS) pcd = (const float*)d_in[i];
    else if (na < 2) adds[na++] = (const float*)d_in[i];
  }
  if (!pcd || na < 2) { pcd = (const float*)d_in[0];
                        adds[0] = (const float*)d_in[1];
                        adds[1] = (const float*)d_in[2]; }

  float* out = (float*)d_out;
  float* out_colors = out + IMG_ELEMS;

  fused_render_kernel<<<NBLK, 256, 0, stream>>>(pcd, adds[0], adds[1],
                                                out, out_colors, cp);
}

// Round 7
// 99.295 us; speedup vs baseline: 4.6545x; 1.3404x over previous
//
#include <hip/hip_runtime.h>
#include <hip/hip_bf16.h>
#include <math.h>

#define NPTS 4096
#define SDIM 128
#define NV 6
#define KTOP 5
#define IMG_ELEMS (NV * SDIM * SDIM * 3)   // 294912

// fp32(0.01*0.01) = 9.99999975e-05 == fp32 literal 1e-4f
#define R2F 1e-4f
#define RMARG 0.0102f        // conservative candidate margin (> radius 0.01)

#define RB 16                // block region: 16x16 pixels
#define NBLK (NV * 64)       // 384 blocks
#define CAP 2048             // LDS candidate capacity (worst block ~530 expected)

struct CamParams { float R[NV][9]; float T[NV][3]; };

__device__ __forceinline__ void process_cand(
    float4 P, float xf, float yf,
    float zk[KTOP], float wk[KTOP], float ck[KTOP]) {
  float dx = xf - P.x;
  float dy = yf - P.y;
  float d2 = dx * dx + dy * dy;
  if (d2 < R2F) {                     // strict, matches ref hit = d2 < R2
    float wgt = 1.0f - d2 / R2F;      // exact ref arithmetic
    float z = P.z;
    if (z < zk[KTOP - 1]) {
      zk[KTOP - 1] = z; wk[KTOP - 1] = wgt; ck[KTOP - 1] = P.w;
#pragma unroll
      for (int k = KTOP - 1; k > 0; k--) {
        if (zk[k] < zk[k - 1]) {
          float tz = zk[k]; zk[k] = zk[k - 1]; zk[k - 1] = tz;
          float tw = wk[k]; wk[k] = wk[k - 1]; wk[k - 1] = tw;
          float tc = ck[k]; ck[k] = ck[k - 1]; ck[k - 1] = tc;
        }
      }
    }
  }
}

// ======== fully fused: vec4 transform + LDS-bin + top-5 + composite ========
__global__ __launch_bounds__(256) void fused_render_kernel(
    const float4* __restrict__ pcd4,     // [3072]  (4096 pts, 3 vec4 per 4 pts)
    const float4* __restrict__ add0_4,   // [1024]
    const float4* __restrict__ add1_4,   // [1024]
    float* __restrict__ out,             // images [6,128,128,3]
    float4* __restrict__ out_colors4,    // colors [1024 float4]
    CamParams cams) {
  int b = blockIdx.x;
  int v = b >> 6;                      // 64 blocks per view
  int t = b & 63;
  int ty = t >> 3, tx = t & 7;
  int tid = threadIdx.x;
  int h = ty * RB + (tid >> 4);
  int w = tx * RB + (tid & 15);
  float xf = (float)(127 - 2 * w) * (1.0f / 128.0f);
  float yf = (float)(127 - 2 * h) * (1.0f / 128.0f);

  // region NDC bounds (xf decreasing in w)
  float xhi = (float)(127 - 2 * (tx * RB)) * (1.0f / 128.0f) + RMARG;
  float xlo = (float)(127 - 2 * (tx * RB + RB - 1)) * (1.0f / 128.0f) - RMARG;
  float yhi = (float)(127 - 2 * (ty * RB)) * (1.0f / 128.0f) + RMARG;
  float ylo = (float)(127 - 2 * (ty * RB + RB - 1)) * (1.0f / 128.0f) - RMARG;

  __shared__ float4 cand[CAP];
  __shared__ int cnt;
  if (tid == 0) cnt = 0;
  __syncthreads();

  const float* Rm = cams.R[v];
  const float* Tm = cams.T[v];
  float R0 = Rm[0], R1 = Rm[1], R2 = Rm[2];
  float R3 = Rm[3], R4 = Rm[4], R5 = Rm[5];
  float R6 = Rm[6], R7 = Rm[7], R8 = Rm[8];
  float T0 = Tm[0], T1 = Tm[1], T2 = Tm[2];

  // ---- phase 1: issue ALL 20 independent vec4 loads up front ----
  float4 A[4][3], C0[4], C1[4];
#pragma unroll
  for (int k = 0; k < 4; k++) {
    int g = k * 256 + tid;             // point-group index (4 pts per group)
    A[k][0] = pcd4[3 * g + 0];
    A[k][1] = pcd4[3 * g + 1];
    A[k][2] = pcd4[3 * g + 2];
    C0[k] = add0_4[g];
    C1[k] = add1_4[g];
  }

#pragma unroll
  for (int k = 0; k < 4; k++) {
    float f[12] = {A[k][0].x, A[k][0].y, A[k][0].z, A[k][0].w,
                   A[k][1].x, A[k][1].y, A[k][1].z, A[k][1].w,
                   A[k][2].x, A[k][2].y, A[k][2].z, A[k][2].w};
    float4 s;
    s.x = 1.0f / (1.0f + expf(-(C0[k].x + C1[k].x)));
    s.y = 1.0f / (1.0f + expf(-(C0[k].y + C1[k].y)));
    s.z = 1.0f / (1.0f + expf(-(C0[k].z + C1[k].z)));
    s.w = 1.0f / (1.0f + expf(-(C0[k].w + C1[k].w)));
    if (b == k) out_colors4[k * 256 + tid] = s;  // blocks 0..3 emit colors once
    float sc[4] = {s.x, s.y, s.z, s.w};
#pragma unroll
    for (int j = 0; j < 4; j++) {
      float p0 = f[3 * j + 0], p1 = f[3 * j + 1], p2 = f[3 * j + 2];
      float px = p0 * R0 + p1 * R3 + p2 * R6 + T0;
      float py = p0 * R1 + p1 * R4 + p2 * R7 + T1;
      float pz = p0 * R2 + p1 * R5 + p2 * R8 + T2;
      if (pz > 0.01f && pz < 100.0f &&
          px > xlo && px < xhi && py > ylo && py < yhi) {
        int idx = atomicAdd(&cnt, 1);
        if (idx < CAP) cand[idx] = make_float4(px, py, pz, sc[j]);
      }
    }
  }
  __syncthreads();

  int n = cnt < CAP ? cnt : CAP;

  float zk[KTOP], wk[KTOP], ck[KTOP];
#pragma unroll
  for (int k = 0; k < KTOP; k++) { zk[k] = 1e30f; wk[k] = 0.0f; ck[k] = 0.0f; }

  // ---- phase 2: candidate scan, 4 independent LDS reads per chunk ----
  int j = 0;
  for (; j + 4 <= n; j += 4) {
    float4 P0 = cand[j + 0];
    float4 P1 = cand[j + 1];
    float4 P2 = cand[j + 2];
    float4 P3 = cand[j + 3];
    process_cand(P0, xf, yf, zk, wk, ck);
    process_cand(P1, xf, yf, zk, wk, ck);
    process_cand(P2, xf, yf, zk, wk, ck);
    process_cand(P3, xf, yf, zk, wk, ck);
  }
  for (; j < n; j++) {
    float4 P = cand[j];
    process_cand(P, xf, yf, zk, wk, ck);
  }

  // front-to-back alpha composite; empty slots w=0 are no-ops (matches ref)
  float acc = 0.0f, pre = 1.0f;
#pragma unroll
  for (int k = 0; k < KTOP; k++) {
    acc += wk[k] * pre * ck[k];
    pre *= (1.0f - wk[k]);
  }

  int base = v * (SDIM * SDIM * 3) + (h * SDIM + w) * 3;
  out[base + 0] = acc;
  out[base + 1] = acc;
  out[base + 2] = acc;
}

// ---------------- host: camera R,T from compile-time constants ----------------
static void compute_cams(CamParams* cp) {
  const double views[NV] = {45.0, 90.0, 135.0, 225.0, 270.0, 315.0};
  const double deg = M_PI / 180.0;
  const double elev = 15.0 * deg;
  const double dist = 1.5;
  for (int v = 0; v < NV; v++) {
    double az = views[v] * deg;
    double C[3] = {dist * cos(elev) * sin(az), dist * sin(elev),
                   dist * cos(elev) * cos(az)};
    double n = sqrt(C[0] * C[0] + C[1] * C[1] + C[2] * C[2]);
    double z[3] = {-C[0] / n, -C[1] / n, -C[2] / n};
    double up[3] = {0.0, 1.0, 0.0};
    double x[3] = {up[1] * z[2] - up[2] * z[1],
                   up[2] * z[0] - up[0] * z[2],
                   up[0] * z[1] - up[1] * z[0]};
    double nx = sqrt(x[0] * x[0] + x[1] * x[1] + x[2] * x[2]);
    x[0] /= nx; x[1] /= nx; x[2] /= nx;
    double y[3] = {z[1] * x[2] - z[2] * x[1],
                   z[2] * x[0] - z[0] * x[2],
                   z[0] * x[1] - z[1] * x[0]};
    double ny = sqrt(y[0] * y[0] + y[1] * y[1] + y[2] * y[2]);
    y[0] /= ny; y[1] /= ny; y[2] /= ny;
    double Rm[3][3];  // columns x, y, z
    for (int j = 0; j < 3; j++) { Rm[j][0] = x[j]; Rm[j][1] = y[j]; Rm[j][2] = z[j]; }
    for (int j = 0; j < 3; j++)
      for (int i = 0; i < 3; i++)
        cp->R[v][j * 3 + i] = (float)Rm[j][i];
    for (int i = 0; i < 3; i++)
      cp->T[v][i] = (float)(-(C[0] * Rm[0][i] + C[1] * Rm[1][i] + C[2] * Rm[2][i]));
  }
}

extern "C" void kernel_launch(void* const* d_in, const int* in_sizes, int n_in,
                              void* d_out, int out_size, void* d_ws, size_t ws_size,
                              hipStream_t stream) {
  CamParams cp;
  compute_cams(&cp);

  // Identify inputs by size (robust to ordering): pcd is the unique 3*NPTS
  // array; the two NPTS arrays are symmetric addends (init_colors + displace).
  const float* pcd = nullptr;
  const float* adds[2] = {nullptr, nullptr};
  int na = 0;
  for (int i = 0; i < n_in; i++) {
    if (in_sizes[i] == 3 * NPTS) pcd = (const float*)d_in[i];
    else if (na < 2) adds[na++] = (const float*)d_in[i];
  }
  if (!pcd || na < 2) { pcd = (const float*)d_in[0];
                        adds[0] = (const float*)d_in[1];
                        adds[1] = (const float*)d_in[2]; }

  float* out = (float*)d_out;
  float4* out_colors4 = (float4*)(out + IMG_ELEMS);   // byte offset %16 == 0

  fused_render_kernel<<<NBLK, 256, 0, stream>>>(
      (const float4*)pcd, (const float4*)adds[0], (const float4*)adds[1],
      out, out_colors4, cp);
}

// Round 8
// 80.078 us; speedup vs baseline: 5.7715x; 1.2400x over previous
//
#include <hip/hip_runtime.h>
#include <hip/hip_bf16.h>
#include <math.h>

#define NPTS 4096
#define SDIM 128
#define NV 6
#define KTOP 5
#define IMG_ELEMS (NV * SDIM * SDIM * 3)   // 294912

// fp32(0.01*0.01) = 9.99999975e-05 == fp32 literal 1e-4f
#define R2F 1e-4f
#define RMARG 0.0102f        // conservative candidate margin (> radius 0.01)

#define RB 16                // block region: 16x16 pixels
#define NBLK (NV * 64)       // 384 blocks
#define NCELL 16             // 4x4 sub-cells of 4x4 pixels each
#define CAPS 256             // per-cell capacity (worst-cell mean ~50; 29 sigma)

struct CamParams { float R[NV][9]; float T[NV][3]; };

__device__ __forceinline__ void process_cand(
    float4 P, float xf, float yf,
    float zk[KTOP], float wk[KTOP], float ck[KTOP]) {
  float dx = xf - P.x;
  float dy = yf - P.y;
  float d2 = dx * dx + dy * dy;
  if (d2 < R2F) {                     // strict, matches ref hit = d2 < R2
    float wgt = 1.0f - d2 / R2F;      // exact ref arithmetic
    float z = P.z;
    if (z < zk[KTOP - 1]) {
      zk[KTOP - 1] = z; wk[KTOP - 1] = wgt; ck[KTOP - 1] = P.w;
#pragma unroll
      for (int k = KTOP - 1; k > 0; k--) {
        if (zk[k] < zk[k - 1]) {
          float tz = zk[k]; zk[k] = zk[k - 1]; zk[k - 1] = tz;
          float tw = wk[k]; wk[k] = wk[k - 1]; wk[k - 1] = tw;
          float tc = ck[k]; ck[k] = ck[k - 1]; ck[k - 1] = tc;
        }
      }
    }
  }
}

// ==== fused: vec4 transform + per-cell LDS bin + per-pixel top-5 + composite ====
__global__ __launch_bounds__(256) void fused_render_kernel(
    const float4* __restrict__ pcd4,     // [3072]
    const float4* __restrict__ add0_4,   // [1024]
    const float4* __restrict__ add1_4,   // [1024]
    float* __restrict__ out,             // images [6,128,128,3]
    float4* __restrict__ out_colors4,    // colors [1024 float4]
    CamParams cams) {
  int b = blockIdx.x;
  int v = b >> 6;                      // 64 blocks per view
  int t = b & 63;
  int ty = t >> 3, tx = t & 7;
  int tid = threadIdx.x;
  int w0 = tx * RB, h0 = ty * RB;      // region origin in pixels
  int h = h0 + (tid >> 4);
  int w = w0 + (tid & 15);
  float xf = (float)(127 - 2 * w) * (1.0f / 128.0f);
  float yf = (float)(127 - 2 * h) * (1.0f / 128.0f);

  // region NDC bounds (xf decreasing in w)
  float xhi = (float)(127 - 2 * w0) * (1.0f / 128.0f) + RMARG;
  float xlo = (float)(127 - 2 * (w0 + RB - 1)) * (1.0f / 128.0f) - RMARG;
  float yhi = (float)(127 - 2 * h0) * (1.0f / 128.0f) + RMARG;
  float ylo = (float)(127 - 2 * (h0 + RB - 1)) * (1.0f / 128.0f) - RMARG;

  // +1 float4 pad: list stride 4112 B -> the 4 lists a wave reads sit on
  // disjoint bank groups (unpadded 4096 B would 4-way conflict)
  __shared__ float4 cand[NCELL][CAPS + 1];
  __shared__ int cnts[NCELL];
  if (tid < NCELL) cnts[tid] = 0;
  __syncthreads();

  const float* Rp = cams.R[v];
  const float* Tp = cams.T[v];
  float R0 = Rp[0], R1 = Rp[1], R2 = Rp[2];
  float R3 = Rp[3], R4 = Rp[4], R5 = Rp[5];
  float R6 = Rp[6], R7 = Rp[7], R8 = Rp[8];
  float T0 = Tp[0], T1 = Tp[1], T2 = Tp[2];

  // ---- phase 1: vec4 loads, transform, append to touched sub-cells ----
  float4 A[4][3], C0[4], C1[4];
#pragma unroll
  for (int k = 0; k < 4; k++) {
    int g = k * 256 + tid;
    A[k][0] = pcd4[3 * g + 0];
    A[k][1] = pcd4[3 * g + 1];
    A[k][2] = pcd4[3 * g + 2];
    C0[k] = add0_4[g];
    C1[k] = add1_4[g];
  }

#pragma unroll
  for (int k = 0; k < 4; k++) {
    float f[12] = {A[k][0].x, A[k][0].y, A[k][0].z, A[k][0].w,
                   A[k][1].x, A[k][1].y, A[k][1].z, A[k][1].w,
                   A[k][2].x, A[k][2].y, A[k][2].z, A[k][2].w};
    float4 s;
    s.x = 1.0f / (1.0f + expf(-(C0[k].x + C1[k].x)));
    s.y = 1.0f / (1.0f + expf(-(C0[k].y + C1[k].y)));
    s.z = 1.0f / (1.0f + expf(-(C0[k].z + C1[k].z)));
    s.w = 1.0f / (1.0f + expf(-(C0[k].w + C1[k].w)));
    if (b == k) out_colors4[k * 256 + tid] = s;  // blocks 0..3 emit colors
    float sc[4] = {s.x, s.y, s.z, s.w};
#pragma unroll
    for (int j = 0; j < 4; j++) {
      float p0 = f[3 * j + 0], p1 = f[3 * j + 1], p2 = f[3 * j + 2];
      float px = p0 * R0 + p1 * R3 + p2 * R6 + T0;
      float py = p0 * R1 + p1 * R4 + p2 * R7 + T1;
      float pz = p0 * R2 + p1 * R5 + p2 * R8 + T2;
      if (pz > 0.01f && pz < 100.0f &&
          px > xlo && px < xhi && py > ylo && py < yhi) {
        // continuous pixel span of this point (w = (127-128*px)/2), local
        float lwlo = (127.0f - 128.0f * (px + RMARG)) * 0.5f - (float)w0;
        float lwhi = (127.0f - 128.0f * (px - RMARG)) * 0.5f - (float)w0;
        float lhlo = (127.0f - 128.0f * (py + RMARG)) * 0.5f - (float)h0;
        float lhhi = (127.0f - 128.0f * (py - RMARG)) * 0.5f - (float)h0;
        int cxlo = (int)fmaxf(0.0f, floorf(lwlo * 0.25f));
        int cxhi = (int)fminf(3.0f, floorf(lwhi * 0.25f));
        int cylo = (int)fmaxf(0.0f, floorf(lhlo * 0.25f));
        int cyhi = (int)fminf(3.0f, floorf(lhhi * 0.25f));
        float4 payload = make_float4(px, py, pz, sc[j]);
        for (int cy = cylo; cy <= cyhi; cy++)
          for (int cx = cxlo; cx <= cxhi; cx++) {
            int li = cy * 4 + cx;
            int idx = atomicAdd(&cnts[li], 1);
            if (idx < CAPS) cand[li][idx] = payload;
          }
      }
    }
  }
  __syncthreads();

  // ---- phase 2: scan own cell's list only ----
  int li = (tid >> 6) * 4 + ((tid >> 2) & 3);   // cy = local_h/4, cx = local_w/4
  int n = cnts[li];
  if (n > CAPS) n = CAPS;
  const float4* list = cand[li];

  float zk[KTOP], wk[KTOP], ck[KTOP];
#pragma unroll
  for (int k = 0; k < KTOP; k++) { zk[k] = 1e30f; wk[k] = 0.0f; ck[k] = 0.0f; }

  int j = 0;
  for (; j + 4 <= n; j += 4) {
    float4 P0 = list[j + 0];
    float4 P1 = list[j + 1];
    float4 P2 = list[j + 2];
    float4 P3 = list[j + 3];
    process_cand(P0, xf, yf, zk, wk, ck);
    process_cand(P1, xf, yf, zk, wk, ck);
    process_cand(P2, xf, yf, zk, wk, ck);
    process_cand(P3, xf, yf, zk, wk, ck);
  }
  for (; j < n; j++) {
    float4 P = list[j];
    process_cand(P, xf, yf, zk, wk, ck);
  }

  // front-to-back alpha composite; empty slots w=0 are no-ops (matches ref)
  float acc = 0.0f, pre = 1.0f;
#pragma unroll
  for (int k = 0; k < KTOP; k++) {
    acc += wk[k] * pre * ck[k];
    pre *= (1.0f - wk[k]);
  }

  int base = v * (SDIM * SDIM * 3) + (h * SDIM + w) * 3;
  out[base + 0] = acc;
  out[base + 1] = acc;
  out[base + 2] = acc;
}

// ---------------- host: camera R,T from compile-time constants ----------------
static void compute_cams(CamParams* cp) {
  const double views[NV] = {45.0, 90.0, 135.0, 225.0, 270.0, 315.0};
  const double deg = M_PI / 180.0;
  const double elev = 15.0 * deg;
  const double dist = 1.5;
  for (int v = 0; v < NV; v++) {
    double az = views[v] * deg;
    double C[3] = {dist * cos(elev) * sin(az), dist * sin(elev),
                   dist * cos(elev) * cos(az)};
    double n = sqrt(C[0] * C[0] + C[1] * C[1] + C[2] * C[2]);
    double z[3] = {-C[0] / n, -C[1] / n, -C[2] / n};
    double up[3] = {0.0, 1.0, 0.0};
    double x[3] = {up[1] * z[2] - up[2] * z[1],
                   up[2] * z[0] - up[0] * z[2],
                   up[0] * z[1] - up[1] * z[0]};
    double nx = sqrt(x[0] * x[0] + x[1] * x[1] + x[2] * x[2]);
    x[0] /= nx; x[1] /= nx; x[2] /= nx;
    double y[3] = {z[1] * x[2] - z[2] * x[1],
                   z[2] * x[0] - z[0] * x[2],
                   z[0] * x[1] - z[1] * x[0]};
    double ny = sqrt(y[0] * y[0] + y[1] * y[1] + y[2] * y[2]);
    y[0] /= ny; y[1] /= ny; y[2] /= ny;
    double Rm[3][3];  // columns x, y, z
    for (int j = 0; j < 3; j++) { Rm[j][0] = x[j]; Rm[j][1] = y[j]; Rm[j][2] = z[j]; }
    for (int j = 0; j < 3; j++)
      for (int i = 0; i < 3; i++)
        cp->R[v][j * 3 + i] = (float)Rm[j][i];
    for (int i = 0; i < 3; i++)
      cp->T[v][i] = (float)(-(C[0] * Rm[0][i] + C[1] * Rm[1][i] + C[2] * Rm[2][i]));
  }
}

extern "C" void kernel_launch(void* const* d_in, const int* in_sizes, int n_in,
                              void* d_out, int out_size, void* d_ws, size_t ws_size,
                              hipStream_t stream) {
  CamParams cp;
  compute_cams(&cp);

  // Identify inputs by size (robust to ordering): pcd is the unique 3*NPTS
  // array; the two NPTS arrays are symmetric addends (init_colors + displace).
  const float* pcd = nullptr;
  const float* adds[2] = {nullptr, nullptr};
  int na = 0;
  for (int i = 0; i < n_in; i++) {
    if (in_sizes[i] == 3 * NPTS) pcd = (const float*)d_in[i];
    else if (na < 2) adds[na++] = (const float*)d_in[i];
  }
  if (!pcd || na < 2) { pcd = (const float*)d_in[0];
                        adds[0] = (const float*)d_in[1];
                        adds[1] = (const float*)d_in[2]; }

  float* out = (float*)d_out;
  float4* out_colors4 = (float4*)(out + IMG_ELEMS);   // byte offset %16 == 0

  fused_render_kernel<<<NBLK, 256, 0, stream>>>(
      (const float4*)pcd, (const float4*)adds[0], (const float4*)adds[1],
      out, out_colors4, cp);
}

// Round 9
// 75.004 us; speedup vs baseline: 6.1619x; 1.0677x over previous
//
#include <hip/hip_runtime.h>
#include <hip/hip_bf16.h>
#include <math.h>

#define NPTS 4096
#define SDIM 128
#define NV 6
#define KTOP 5
#define IMG_ELEMS (NV * SDIM * SDIM * 3)   // 294912

// fp32(0.01*0.01) = 9.99999975e-05 == fp32 literal 1e-4f
#define R2F 1e-4f
#define RMARG 0.0102f        // conservative candidate margin (> radius 0.01)

#define RBW 32               // region: 32 px wide x 16 px tall, 512 threads
#define RBH 16
#define NBLK (NV * 32)       // (128/32)*(128/16)=32 regions/view -> 192 blocks
#define NCX 8                // 8x4 sub-cells of 4x4 px
#define NCY 4
#define NCELL 32
#define CAPS 128             // per-cell capacity (worst-cell mean ~50, Poisson-safe)

struct CamParams { float R[NV][9]; float T[NV][3]; };

__device__ __forceinline__ float sigmoidf_fast(float x) {
  return __fdividef(1.0f, 1.0f + __expf(-x));
}

__device__ __forceinline__ void process_cand(
    float4 P, float xf, float yf,
    float zk[KTOP], float wk[KTOP], float ck[KTOP]) {
  float dx = xf - P.x;
  float dy = yf - P.y;
  float d2 = dx * dx + dy * dy;
  if (d2 < R2F) {                     // strict, matches ref hit = d2 < R2
    float wgt = 1.0f - d2 / R2F;      // exact ref arithmetic
    float z = P.z;
    if (z < zk[KTOP - 1]) {
      zk[KTOP - 1] = z; wk[KTOP - 1] = wgt; ck[KTOP - 1] = P.w;
#pragma unroll
      for (int k = KTOP - 1; k > 0; k--) {
        if (zk[k] < zk[k - 1]) {      // strict: stable (lower idx first) on ties
          float tz = zk[k]; zk[k] = zk[k - 1]; zk[k - 1] = tz;
          float tw = wk[k]; wk[k] = wk[k - 1]; wk[k - 1] = tw;
          float tc = ck[k]; ck[k] = ck[k - 1]; ck[k - 1] = tc;
        }
      }
    }
  }
}

// ==== fused: vec4 transform + per-cell LDS bin + per-pixel top-5 + composite ====
__global__ __launch_bounds__(512) void fused_render_kernel(
    const float4* __restrict__ pcd4,     // [3072]
    const float4* __restrict__ add0_4,   // [1024]
    const float4* __restrict__ add1_4,   // [1024]
    float* __restrict__ out,             // images [6,128,128,3]
    float4* __restrict__ out_colors4,    // colors [1024 float4]
    CamParams cams) {
  int b = blockIdx.x;
  int v = b >> 5;                      // 32 blocks per view
  int t = b & 31;
  int ty = t >> 2, tx = t & 3;         // 4 cols x 8 rows of regions
  int tid = threadIdx.x;
  int w0 = tx * RBW, h0 = ty * RBH;    // region origin in pixels
  int row = tid >> 5, col = tid & 31;  // 16 rows x 32 cols
  int h = h0 + row;
  int w = w0 + col;
  float xf = (float)(127 - 2 * w) * (1.0f / 128.0f);
  float yf = (float)(127 - 2 * h) * (1.0f / 128.0f);

  // region NDC bounds (xf decreasing in w)
  float xhi = (float)(127 - 2 * w0) * (1.0f / 128.0f) + RMARG;
  float xlo = (float)(127 - 2 * (w0 + RBW - 1)) * (1.0f / 128.0f) - RMARG;
  float yhi = (float)(127 - 2 * h0) * (1.0f / 128.0f) + RMARG;
  float ylo = (float)(127 - 2 * (h0 + RBH - 1)) * (1.0f / 128.0f) - RMARG;

  // +1 float4 pad: stride 2064 B -> the 8 lists a wave reads start on banks
  // {0,4,...,28}; each b128 spans a disjoint bank quad -> conflict-free.
  __shared__ float4 cand[NCELL][CAPS + 1];
  __shared__ int cnts[NCELL];
  if (tid < NCELL) cnts[tid] = 0;
  __syncthreads();

  const float* Rp = cams.R[v];
  const float* Tp = cams.T[v];
  float R0 = Rp[0], R1 = Rp[1], R2 = Rp[2];
  float R3 = Rp[3], R4 = Rp[4], R5 = Rp[5];
  float R6 = Rp[6], R7 = Rp[7], R8 = Rp[8];
  float T0 = Tp[0], T1 = Tp[1], T2 = Tp[2];

  // ---- phase 1: 10 vec4 loads up front, transform 8 pts, bin to sub-cells ----
  float4 A[2][3], C0[2], C1[2];
#pragma unroll
  for (int k = 0; k < 2; k++) {
    int g = k * 512 + tid;             // point-group (4 pts per group)
    A[k][0] = pcd4[3 * g + 0];
    A[k][1] = pcd4[3 * g + 1];
    A[k][2] = pcd4[3 * g + 2];
    C0[k] = add0_4[g];
    C1[k] = add1_4[g];
  }

  // blocks 0,1 (view-0 corner regions, light phase 2) emit the colors output
  if (b < 2) {
    int g = b * 512 + tid;
    float4 s;
    s.x = sigmoidf_fast(C0[b].x + C1[b].x);
    s.y = sigmoidf_fast(C0[b].y + C1[b].y);
    s.z = sigmoidf_fast(C0[b].z + C1[b].z);
    s.w = sigmoidf_fast(C0[b].w + C1[b].w);
    out_colors4[g] = s;
  }

#pragma unroll
  for (int k = 0; k < 2; k++) {
    float f[12] = {A[k][0].x, A[k][0].y, A[k][0].z, A[k][0].w,
                   A[k][1].x, A[k][1].y, A[k][1].z, A[k][1].w,
                   A[k][2].x, A[k][2].y, A[k][2].z, A[k][2].w};
    float sc[4] = {sigmoidf_fast(C0[k].x + C1[k].x),
                   sigmoidf_fast(C0[k].y + C1[k].y),
                   sigmoidf_fast(C0[k].z + C1[k].z),
                   sigmoidf_fast(C0[k].w + C1[k].w)};
#pragma unroll
    for (int j = 0; j < 4; j++) {
      float p0 = f[3 * j + 0], p1 = f[3 * j + 1], p2 = f[3 * j + 2];
      float px = p0 * R0 + p1 * R3 + p2 * R6 + T0;
      float py = p0 * R1 + p1 * R4 + p2 * R7 + T1;
      float pz = p0 * R2 + p1 * R5 + p2 * R8 + T2;
      if (pz > 0.01f && pz < 100.0f &&
          px > xlo && px < xhi && py > ylo && py < yhi) {
        // continuous local pixel span (w = (127-128*px)/2)
        float lwlo = (127.0f - 128.0f * (px + RMARG)) * 0.5f - (float)w0;
        float lwhi = (127.0f - 128.0f * (px - RMARG)) * 0.5f - (float)w0;
        float lhlo = (127.0f - 128.0f * (py + RMARG)) * 0.5f - (float)h0;
        float lhhi = (127.0f - 128.0f * (py - RMARG)) * 0.5f - (float)h0;
        int cxlo = (int)fmaxf(0.0f, floorf(lwlo * 0.25f));
        int cxhi = (int)fminf((float)(NCX - 1), floorf(lwhi * 0.25f));
        int cylo = (int)fmaxf(0.0f, floorf(lhlo * 0.25f));
        int cyhi = (int)fminf((float)(NCY - 1), floorf(lhhi * 0.25f));
        float4 payload = make_float4(px, py, pz, sc[j]);
        for (int cy = cylo; cy <= cyhi; cy++)
          for (int cx = cxlo; cx <= cxhi; cx++) {
            int li = cy * NCX + cx;
            int idx = atomicAdd(&cnts[li], 1);
            if (idx < CAPS) cand[li][idx] = payload;
          }
      }
    }
  }
  __syncthreads();

  // ---- phase 2: scan own 4x4-px cell's list (false positives re-tested) ----
  int li = (row >> 2) * NCX + (col >> 2);
  int n = cnts[li];
  if (n > CAPS) n = CAPS;
  const float4* list = cand[li];

  float zk[KTOP], wk[KTOP], ck[KTOP];
#pragma unroll
  for (int k = 0; k < KTOP; k++) { zk[k] = 1e30f; wk[k] = 0.0f; ck[k] = 0.0f; }

  int j = 0;
  for (; j + 8 <= n; j += 8) {
    float4 P0 = list[j + 0], P1 = list[j + 1], P2 = list[j + 2], P3 = list[j + 3];
    float4 P4 = list[j + 4], P5 = list[j + 5], P6 = list[j + 6], P7 = list[j + 7];
    process_cand(P0, xf, yf, zk, wk, ck);
    process_cand(P1, xf, yf, zk, wk, ck);
    process_cand(P2, xf, yf, zk, wk, ck);
    process_cand(P3, xf, yf, zk, wk, ck);
    process_cand(P4, xf, yf, zk, wk, ck);
    process_cand(P5, xf, yf, zk, wk, ck);
    process_cand(P6, xf, yf, zk, wk, ck);
    process_cand(P7, xf, yf, zk, wk, ck);
  }
  for (; j < n; j++) {
    float4 P = list[j];
    process_cand(P, xf, yf, zk, wk, ck);
  }

  // front-to-back alpha composite; empty slots w=0 are no-ops (matches ref)
  float acc = 0.0f, pre = 1.0f;
#pragma unroll
  for (int k = 0; k < KTOP; k++) {
    acc += wk[k] * pre * ck[k];
    pre *= (1.0f - wk[k]);
  }

  int base = v * (SDIM * SDIM * 3) + (h * SDIM + w) * 3;
  out[base + 0] = acc;
  out[base + 1] = acc;
  out[base + 2] = acc;
}

// ---------------- host: camera R,T from compile-time constants ----------------
static void compute_cams(CamParams* cp) {
  const double views[NV] = {45.0, 90.0, 135.0, 225.0, 270.0, 315.0};
  const double deg = M_PI / 180.0;
  const double elev = 15.0 * deg;
  const double dist = 1.5;
  for (int v = 0; v < NV; v++) {
    double az = views[v] * deg;
    double C[3] = {dist * cos(elev) * sin(az), dist * sin(elev),
                   dist * cos(elev) * cos(az)};
    double n = sqrt(C[0] * C[0] + C[1] * C[1] + C[2] * C[2]);
    double z[3] = {-C[0] / n, -C[1] / n, -C[2] / n};
    double up[3] = {0.0, 1.0, 0.0};
    double x[3] = {up[1] * z[2] - up[2] * z[1],
                   up[2] * z[0] - up[0] * z[2],
                   up[0] * z[1] - up[1] * z[0]};
    double nx = sqrt(x[0] * x[0] + x[1] * x[1] + x[2] * x[2]);
    x[0] /= nx; x[1] /= nx; x[2] /= nx;
    double y[3] = {z[1] * x[2] - z[2] * x[1],
                   z[2] * x[0] - z[0] * x[2],
                   z[0] * x[1] - z[1] * x[0]};
    double ny = sqrt(y[0] * y[0] + y[1] * y[1] + y[2] * y[2]);
    y[0] /= ny; y[1] /= ny; y[2] /= ny;
    double Rm[3][3];  // columns x, y, z
    for (int j = 0; j < 3; j++) { Rm[j][0] = x[j]; Rm[j][1] = y[j]; Rm[j][2] = z[j]; }
    for (int j = 0; j < 3; j++)
      for (int i = 0; i < 3; i++)
        cp->R[v][j * 3 + i] = (float)Rm[j][i];
    for (int i = 0; i < 3; i++)
      cp->T[v][i] = (float)(-(C[0] * Rm[0][i] + C[1] * Rm[1][i] + C[2] * Rm[2][i]));
  }
}

extern "C" void kernel_launch(void* const* d_in, const int* in_sizes, int n_in,
                              void* d_out, int out_size, void* d_ws, size_t ws_size,
                              hipStream_t stream) {
  CamParams cp;
  compute_cams(&cp);

  // Identify inputs by size (robust to ordering): pcd is the unique 3*NPTS
  // array; the two NPTS arrays are symmetric addends (init_colors + displace).
  const float* pcd = nullptr;
  const float* adds[2] = {nullptr, nullptr};
  int na = 0;
  for (int i = 0; i < n_in; i++) {
    if (in_sizes[i] == 3 * NPTS) pcd = (const float*)d_in[i];
    else if (na < 2) adds[na++] = (const float*)d_in[i];
  }
  if (!pcd || na < 2) { pcd = (const float*)d_in[0];
                        adds[0] = (const float*)d_in[1];
                        adds[1] = (const float*)d_in[2]; }

  float* out = (float*)d_out;
  float4* out_colors4 = (float4*)(out + IMG_ELEMS);   // byte offset %16 == 0

  fused_render_kernel<<<NBLK, 512, 0, stream>>>(
      (const float4*)pcd, (const float4*)adds[0], (const float4*)adds[1],
      out, out_colors4, cp);
}